// Round 7
// baseline (195.898 us; speedup 1.0000x reference)
//
#include <hip/hip_runtime.h>

// SVSAlgorithm: per-pixel sequential threshold recurrence over T frames,
// fused with 3x3 constant-kernel "DiffErosion" conv + relu epilogue.
//
// Two-launch design:
//  L1 svs_scan<SNAP>: 64-thread blocks, 2 pixel-chains/thread (float2 loads
//     -> 512B contiguous per wave-instruction for DRAM page locality; R6's
//     256B segments at 80KB stride ran at ~2.8 TB/s). 4-deep rotating batch
//     pipeline (4 x 16 float2 loads) ~ 64 outstanding loads/wave ~ vmcnt cap.
//     Snapshots (HT,LT) every SNAP frames to d_ws as one float4/thread.
//     Own kernel => own regalloc, __launch_bounds__(64,1), no spill.
//  L2 svs_compute<SNAP>: 16x16 tile (14x14 interior + halo recompute), one
//     block per (tile, SNAP-frame slice); SNAP=64 -> 3840 blocks. Sigmoid via
//     exp2(fma)+v_rcp; conv == box-sum (all 9 weights equal): vertical =
//     2 LDS reads + own register, horizontal via DPP row_shr/row_shl. LDS
//     sm[row][frame][col] (row stride 136 == 8 mod 32 banks -> <=2-way).
//     XCD-grouped block remap for output-line merging in L2.
//  State updates replicate reference f32 op order exactly.
//  ws ladder: SNAP=64 (5.1MB) -> SNAP=128 (2.4MB) -> fused fallback.

#define TILE_W 16
#define TILE_H 16
#define IN_W 14
#define IN_H 14
#define BUF 8        // frames per LDS stage in compute pass
#define SB 16        // scan batch: frames per batch (4 batches in flight)

constexpr int T_FRAMES = 2048;
constexpr int H_IMG = 128;
constexpr int W_IMG = 160;
constexpr int HW = H_IMG * W_IMG;
constexpr float C1 = 721.3475204444817f;         // 500 * log2(e)

constexpr size_t ws_needed(int snap) {
    return (size_t)(T_FRAMES / snap - 1) * HW * sizeof(float2);
}

__device__ __forceinline__ float dpp_from_left(float v) {   // lane n <- lane n-1 (16-lane rows)
    return __int_as_float(__builtin_amdgcn_update_dpp(0, __float_as_int(v), 0x111, 0xF, 0xF, true));
}
__device__ __forceinline__ float dpp_from_right(float v) {  // lane n <- lane n+1
    return __int_as_float(__builtin_amdgcn_update_dpp(0, __float_as_int(v), 0x101, 0xF, 0xF, true));
}

// ---------------- L1: state-only scan, float2 chains, 4-deep pipeline -----
#define S_ISSUE(V, F)                              \
    _Pragma("unroll")                              \
    for (int i = 0; i < SB; ++i) V[i] = xp2[((F) + i) * (HW / 2)];

#define S_COMP(V)                                  \
    _Pragma("unroll")                              \
    for (int i = 0; i < SB; ++i) {                 \
        const float ix = V[i].x, iy = V[i].y;      \
        HTx = ((ix - HTx) > 0.0f) ? (HTx + dO) : (HTx - dC); \
        LTx = ((LTx - ix) > 0.0f) ? (LTx - dO) : (LTx + dC); \
        HTy = ((iy - HTy) > 0.0f) ? (HTy + dO) : (HTy - dC); \
        LTy = ((LTy - iy) > 0.0f) ? (LTy - dO) : (LTy + dC); \
    }

template <int SNAP_>
__global__ __launch_bounds__(64, 1)
void svs_scan(const float* __restrict__ x, const float* __restrict__ params,
              const float* __restrict__ HT0, const float* __restrict__ LT0,
              float4* __restrict__ snap4)
{
    static_assert(SNAP_ % (4 * SB) == 0, "snapshot boundary must align to pipeline macro-iter");
    const int pix2 = (int)blockIdx.x * 64 + (int)threadIdx.x;  // chain-pair id; 160 blocks
    const float dC = params[0];
    const float dO = params[1];

    const float2 h0 = ((const float2*)HT0)[pix2];
    const float2 l0 = ((const float2*)LT0)[pix2];
    float HTx = h0.x, HTy = h0.y, LTx = l0.x, LTy = l0.y;
    const float2* xp2 = (const float2*)x + pix2;

    float2 v0[SB], v1[SB], v2[SB], v3[SB];
    S_ISSUE(v0, 0)
    S_ISSUE(v1, SB)
    S_ISSUE(v2, 2 * SB)
    S_ISSUE(v3, 3 * SB)

    for (int t = 0; t < T_FRAMES; t += 4 * SB) {
        const bool more = (t + 4 * SB) < T_FRAMES;
        S_COMP(v0)
        if (more) { S_ISSUE(v0, t + 4 * SB) }
        S_COMP(v1)
        if (more) { S_ISSUE(v1, t + 5 * SB) }
        S_COMP(v2)
        if (more) { S_ISSUE(v2, t + 6 * SB) }
        S_COMP(v3)
        if (more) { S_ISSUE(v3, t + 7 * SB) }
        // state now holds frame t+4*SB-1; snapshot boundary every SNAP_ frames
        if (((t + 4 * SB) % SNAP_) == 0) {
            const int k = (t + 4 * SB) / SNAP_ - 1;
            if (k < T_FRAMES / SNAP_ - 1)
                snap4[(size_t)k * (HW / 2) + pix2] = make_float4(HTx, LTx, HTy, LTy);
        }
    }
}

// ---------------- L2: per-slice fused compute -----------------------------
template <int SNAP_>
__global__ __launch_bounds__(256)
void svs_compute(const float* __restrict__ x, const float* __restrict__ params,
                 const float* __restrict__ HT0, const float* __restrict__ LT0,
                 const float* __restrict__ kern, const float2* __restrict__ snap,
                 float* __restrict__ out)
{
    constexpr int NSLICE_ = T_FRAMES / SNAP_;
    constexpr int TOTAL_ = 120 * NSLICE_;
    // XCD-grouped remap: contiguous chunks of linear block id per XCD so
    // adjacent-bx tiles (sharing output cache lines) land on one XCD L2.
    const int lin = (int)blockIdx.x + 12 * (int)blockIdx.y + 120 * (int)blockIdx.z;
    const int w   = (lin & 7) * (TOTAL_ / 8) + (lin >> 3);   // TOTAL_%8==0 -> bijective
    const int bx  = w % 12;
    const int by  = (w / 12) % 10;
    const int slice = w / 120;

    const int tx = threadIdx.x & 15;
    const int ty = threadIdx.x >> 4;
    const int gx = bx * IN_W + tx - 1;
    const int gy = by * IN_H + ty - 1;
    const int t0 = slice * SNAP_;

    const bool valid = (gx >= 0) & (gx < W_IMG) & (gy >= 0) & (gy < H_IMG);
    const int cx = min(max(gx, 0), W_IMG - 1);
    const int cy = min(max(gy, 0), H_IMG - 1);
    const int pix = cy * W_IMG + cx;

    const float dC   = params[0];
    const float dO   = params[1];
    const float dHot = params[2];
    const float kw   = kern[4];        // all 9 weights equal (2/9)
    const float c0   = dHot * C1;      // exp2 arg = fma(a, -C1, c0)

    float HT, LT;
    if (slice == 0) {
        HT = valid ? HT0[pix] : 0.0f;
        LT = valid ? LT0[pix] : 0.0f;
    } else {
        const float2 s = snap[(size_t)(slice - 1) * HW + pix];
        HT = valid ? s.x : 0.0f;
        LT = valid ? s.y : 0.0f;
    }

    // sm[row][frame][col]: row stride 136 floats == 8 mod 32 banks ->
    // wave's 4 row-clusters at bank shifts {0,8,16,24}: <=2-way (free).
    __shared__ float sm[TILE_H][BUF][TILE_W + 1];

    const bool doOut = (tx >= 1) & (tx <= IN_W) & (ty >= 1) & (ty <= IN_H) & valid;
    const int ym = max(ty - 1, 0);
    const int yp = min(ty + 1, TILE_H - 1);
    const float* xp = x + pix;
    float* op = out + pix;

    for (int tb = t0; tb < t0 + SNAP_; tb += BUF) {
        float v[BUF], hot[BUF];
        #pragma unroll
        for (int i = 0; i < BUF; ++i) v[i] = xp[(tb + i) * HW];
        #pragma unroll
        for (int i = 0; i < BUF; ++i) {
            const float img = v[i];
            const float aH = img - HT;
            const float eH = __builtin_amdgcn_exp2f(fmaf(aH, -C1, c0));
            const float hH = __builtin_amdgcn_rcpf(1.0f + eH);
            HT = (aH > 0.0f) ? (HT + dO) : (HT - dC);
            const float aL = LT - img;
            const float eL = __builtin_amdgcn_exp2f(fmaf(aL, -C1, c0));
            const float hL = __builtin_amdgcn_rcpf(1.0f + eL);
            LT = (aL > 0.0f) ? (LT - dO) : (LT + dC);
            hot[i] = valid ? (hH + hL) : 1.0f;
            sm[ty][i][tx] = hot[i];
        }
        __syncthreads();
        #pragma unroll
        for (int i = 0; i < BUF; ++i) {
            const float r0 = sm[ym][i][tx];
            const float r1 = sm[yp][i][tx];
            const float vs = r0 + hot[i] + r1;               // vertical box sum
            const float S  = vs + dpp_from_left(vs) + dpp_from_right(vs);
            float o = fmaf(S, kw, -1.0f);                    // 1 - kw*(9-S) = kw*S - 1
            o = fmaxf(o, 0.0f);
            if (doOut) op[(tb + i) * HW] = o;
        }
        __syncthreads();
    }
}

// ---------------- Fallback: fused kernel (if ws too small) ----------------
#define NCHUNK 8
constexpr int CHUNK = T_FRAMES / NCHUNK;

__global__ __launch_bounds__(256)
void svs_fused(const float* __restrict__ x, const float* __restrict__ params,
               const float* __restrict__ HT0, const float* __restrict__ LT0,
               const float* __restrict__ kern, float* __restrict__ out)
{
    const int tx = threadIdx.x & 15;
    const int ty = threadIdx.x >> 4;
    const int gx = (int)blockIdx.x * IN_W + tx - 1;
    const int gy = (int)blockIdx.y * IN_H + ty - 1;
    const int chunk = (NCHUNK - 1) - (int)blockIdx.z;

    const bool valid = (gx >= 0) & (gx < W_IMG) & (gy >= 0) & (gy < H_IMG);
    const int cx = min(max(gx, 0), W_IMG - 1);
    const int cy = min(max(gy, 0), H_IMG - 1);
    const int pix = cy * W_IMG + cx;

    const float dC   = params[0];
    const float dO   = params[1];
    const float dHot = params[2];
    const float kw   = kern[4];

    float HT = valid ? HT0[pix] : 0.0f;
    float LT = valid ? LT0[pix] : 0.0f;

    const float* xp = x + pix;
    const int t0 = chunk * CHUNK;

    for (int t = 0; t < t0; t += BUF) {
        float v[BUF];
        #pragma unroll
        for (int i = 0; i < BUF; ++i) v[i] = xp[(t + i) * HW];
        #pragma unroll
        for (int i = 0; i < BUF; ++i) {
            const float img = v[i];
            HT = ((img - HT) > 0.0f) ? (HT + dO) : (HT - dC);
            LT = ((LT - img) > 0.0f) ? (LT - dO) : (LT + dC);
        }
    }

    __shared__ float sm[TILE_H][BUF][TILE_W + 1];
    const bool doOut = (tx >= 1) & (tx <= IN_W) & (ty >= 1) & (ty <= IN_H) & valid;
    const int ym = max(ty - 1, 0);
    const int yp = min(ty + 1, TILE_H - 1);
    const float c0 = dHot * C1;
    float* op = out + pix;

    for (int tb = t0; tb < t0 + CHUNK; tb += BUF) {
        float v[BUF], hot[BUF];
        #pragma unroll
        for (int i = 0; i < BUF; ++i) v[i] = xp[(tb + i) * HW];
        #pragma unroll
        for (int i = 0; i < BUF; ++i) {
            const float img = v[i];
            const float aH = img - HT;
            const float eH = __builtin_amdgcn_exp2f(fmaf(aH, -C1, c0));
            const float hH = __builtin_amdgcn_rcpf(1.0f + eH);
            HT = (aH > 0.0f) ? (HT + dO) : (HT - dC);
            const float aL = LT - img;
            const float eL = __builtin_amdgcn_exp2f(fmaf(aL, -C1, c0));
            const float hL = __builtin_amdgcn_rcpf(1.0f + eL);
            LT = (aL > 0.0f) ? (LT - dO) : (LT + dC);
            hot[i] = valid ? (hH + hL) : 1.0f;
            sm[ty][i][tx] = hot[i];
        }
        __syncthreads();
        #pragma unroll
        for (int i = 0; i < BUF; ++i) {
            const float r0 = sm[ym][i][tx];
            const float r1 = sm[yp][i][tx];
            const float vs = r0 + hot[i] + r1;
            const float S  = vs + dpp_from_left(vs) + dpp_from_right(vs);
            float o = fmaf(S, kw, -1.0f);
            o = fmaxf(o, 0.0f);
            if (doOut) op[(tb + i) * HW] = o;
        }
        __syncthreads();
    }
}

extern "C" void kernel_launch(void* const* d_in, const int* in_sizes, int n_in,
                              void* d_out, int out_size, void* d_ws, size_t ws_size,
                              hipStream_t stream) {
    const float* x      = (const float*)d_in[0];
    const float* params = (const float*)d_in[1];
    const float* HT0p   = (const float*)d_in[2];
    const float* LT0p   = (const float*)d_in[3];
    const float* kern   = (const float*)d_in[4];
    float* out = (float*)d_out;

    if (ws_size >= ws_needed(64)) {
        svs_scan<64><<<dim3(HW / 128), dim3(64), 0, stream>>>(
            x, params, HT0p, LT0p, (float4*)d_ws);
        svs_compute<64><<<dim3(12, 10, T_FRAMES / 64), dim3(256), 0, stream>>>(
            x, params, HT0p, LT0p, kern, (const float2*)d_ws, out);
    } else if (ws_size >= ws_needed(128)) {
        svs_scan<128><<<dim3(HW / 128), dim3(64), 0, stream>>>(
            x, params, HT0p, LT0p, (float4*)d_ws);
        svs_compute<128><<<dim3(12, 10, T_FRAMES / 128), dim3(256), 0, stream>>>(
            x, params, HT0p, LT0p, kern, (const float2*)d_ws, out);
    } else {
        dim3 grid((W_IMG + IN_W - 1) / IN_W, (H_IMG + IN_H - 1) / IN_H, NCHUNK);
        svs_fused<<<grid, dim3(256), 0, stream>>>(x, params, HT0p, LT0p, kern, out);
    }
}